// Round 1
// baseline (4000.129 us; speedup 1.0000x reference)
//
#include <hip/hip_runtime.h>
#include <cstdint>
#include <cstddef>

// Problem constants
#define BB 2
#define TT 2048
#define DMODEL 1024
#define NHEADS 16
#define DK 64

typedef short short8 __attribute__((ext_vector_type(8)));
typedef float floatx4 __attribute__((ext_vector_type(4)));

// ---------- helpers ----------
__device__ __forceinline__ unsigned short f2bf(float f) {
    uint32_t u = __builtin_bit_cast(uint32_t, f);
    uint32_t r = (u + 0x7FFFu + ((u >> 16) & 1u)) >> 16;
    return (unsigned short)r;
}

// ---------- cast fp32 -> bf16 (vector x4) ----------
__global__ void castk(const float* __restrict__ in, unsigned short* __restrict__ out, int n) {
    int i = (blockIdx.x * blockDim.x + threadIdx.x) * 4;
    if (i >= n) return;
    float4 v = *(const float4*)(in + i);
    ushort4 o;
    o.x = f2bf(v.x); o.y = f2bf(v.y); o.z = f2bf(v.z); o.w = f2bf(v.w);
    *(ushort4*)(out + i) = o;
}

// ---------- bf16 MFMA GEMM, C = A * B^T  (A: [M][K], B: [N][K], C fp32 [M][N]) ----------
// m97 structure: 128x128 tile, BK=32, 4 waves (2x2), each wave 64x64 = 4x4 MFMA tiles.
#define GLDS16(g, l) __builtin_amdgcn_global_load_lds( \
    (const __attribute__((address_space(1))) void*)(g), \
    (__attribute__((address_space(3))) void*)(l), 16, 0, 0)

__global__ __launch_bounds__(256)
void gemm_bt(const unsigned short* __restrict__ A, const unsigned short* __restrict__ B,
             float* __restrict__ C, int M, int N, int K) {
    __shared__ unsigned short As[128 * 32];
    __shared__ unsigned short Bs[128 * 32];

    const int tid  = threadIdx.x;
    const int lane = tid & 63;
    const int w    = tid >> 6;      // wave id 0..3
    const int wm   = w & 1;
    const int wn   = w >> 1;
    const int quad = lane >> 4;     // 0..3
    const int l16  = lane & 15;

    const int m0 = blockIdx.y * 128;
    const int n0 = blockIdx.x * 128;

    floatx4 acc[4][4];
#pragma unroll
    for (int a = 0; a < 4; a++)
#pragma unroll
        for (int b = 0; b < 4; b++)
            acc[a][b] = (floatx4){0.f, 0.f, 0.f, 0.f};

    // staging chunks: 512 chunks of 16B (8 bf16) per tile; each thread does 2.
    const int c0 = w * 128 + lane;       // it = 0
    const int c1 = c0 + 64;              // it = 1
    const int r0 = c0 >> 2, cc0 = c0 & 3;
    const int r1 = c1 >> 2, cc1 = c1 & 3;

    const unsigned short* gA0 = A + (size_t)(m0 + r0) * K + cc0 * 8;
    const unsigned short* gA1 = A + (size_t)(m0 + r1) * K + cc1 * 8;
    const unsigned short* gB0 = B + (size_t)(n0 + r0) * K + cc0 * 8;
    const unsigned short* gB1 = B + (size_t)(n0 + r1) * K + cc1 * 8;

    unsigned short* lA0 = &As[(2 * w + 0) * 512];
    unsigned short* lA1 = &As[(2 * w + 1) * 512];
    unsigned short* lB0 = &Bs[(2 * w + 0) * 512];
    unsigned short* lB1 = &Bs[(2 * w + 1) * 512];

    for (int k0 = 0; k0 < K; k0 += 32) {
        __syncthreads();   // protect LDS from previous iteration's readers
        GLDS16(gA0 + k0, lA0);
        GLDS16(gA1 + k0, lA1);
        GLDS16(gB0 + k0, lB0);
        GLDS16(gB1 + k0, lB1);
        __syncthreads();   // compiler emits s_waitcnt vmcnt(0) before barrier

        short8 af[4], bf[4];
#pragma unroll
        for (int t = 0; t < 4; t++) {
            af[t] = *(const short8*)&As[(wm * 64 + t * 16 + l16) * 32 + quad * 8];
            bf[t] = *(const short8*)&Bs[(wn * 64 + t * 16 + l16) * 32 + quad * 8];
        }
#pragma unroll
        for (int tm = 0; tm < 4; tm++)
#pragma unroll
            for (int tn = 0; tn < 4; tn++)
                acc[tm][tn] = __builtin_amdgcn_mfma_f32_16x16x32_bf16(
                    af[tm], bf[tn], acc[tm][tn], 0, 0, 0);
    }

    // epilogue: C/D layout col = lane&15, row = quad*4 + reg   (m89-verified)
#pragma unroll
    for (int tm = 0; tm < 4; tm++) {
#pragma unroll
        for (int tn = 0; tn < 4; tn++) {
#pragma unroll
            for (int r = 0; r < 4; r++) {
                int m = m0 + wm * 64 + tm * 16 + quad * 4 + r;
                int n = n0 + wn * 64 + tn * 16 + l16;
                C[(size_t)m * N + n] = acc[tm][tn][r];
            }
        }
    }
}

// ---------- RoPE + split/transpose: qkv [B*T][3072] fp32 -> qT,kT,vT [B][H][T][64] fp32 ----------
__global__ void rope_split(const float* __restrict__ qkv, float* __restrict__ qT,
                           float* __restrict__ kT, float* __restrict__ vT) {
    int idx = blockIdx.x * blockDim.x + threadIdx.x;   // 2^21 threads, one per (b,t,h,pair)
    int p = idx & 31;
    int h = (idx >> 5) & 15;
    int t = (idx >> 9) & 2047;
    int b = idx >> 20;

    size_t src = (size_t)(b * TT + t) * 3072 + h * 64 + 2 * p;
    float2 q = *(const float2*)(qkv + src);
    float2 k = *(const float2*)(qkv + src + 1024);
    float2 v = *(const float2*)(qkv + src + 2048);

    float invf = __powf(10000.f, -((float)(2 * p)) / 64.f);
    float ang  = (float)t * invf;
    float sn, cs;
    __sincosf(ang, &sn, &cs);

    size_t dst = ((size_t)(b * NHEADS + h) * TT + t) * 64 + 2 * p;
    float2 qo; qo.x = q.x * cs - q.y * sn; qo.y = q.y * cs + q.x * sn;
    float2 ko; ko.x = k.x * cs - k.y * sn; ko.y = k.y * cs + k.x * sn;
    *(float2*)(qT + dst) = qo;
    *(float2*)(kT + dst) = ko;
    *(float2*)(vT + dst) = v;
}

// ---------- causal flash attention, fp32, one thread per q-row ----------
// K/V addresses are thread-uniform (j loop uniform) -> scalar loads; VALU does the math.
__global__ __launch_bounds__(64)
void attn_fp32(const float* __restrict__ qT, const float* __restrict__ kT,
               const float* __restrict__ vT, unsigned short* __restrict__ out) {
    const int bh   = blockIdx.y;           // b*16 + h
    const int b    = bh >> 4;
    const int h    = bh & 15;
    const int tile = blockIdx.x;
    const int i    = tile * 64 + threadIdx.x;   // my q row

    const float* Q  = qT + (size_t)bh * TT * 64;
    const float* Kp = kT + (size_t)bh * TT * 64;
    const float* Vp = vT + (size_t)bh * TT * 64;

    float4 q[16];
#pragma unroll
    for (int u = 0; u < 16; u++) q[u] = *(const float4*)(Q + (size_t)i * 64 + u * 4);
    float4 o[16];
#pragma unroll
    for (int u = 0; u < 16; u++) o[u] = make_float4(0.f, 0.f, 0.f, 0.f);

    float m = -1e30f, l = 0.f;
    const int jmax = tile * 64 + 64;

    for (int jc = 0; jc < jmax; jc += 8) {
        float s[8];
#pragma unroll
        for (int jj = 0; jj < 8; jj++) {
            const float4* kr = (const float4*)(Kp + (size_t)(jc + jj) * 64);
            float a0 = 0.f, a1 = 0.f, a2 = 0.f, a3 = 0.f;
#pragma unroll
            for (int u = 0; u < 16; u++) {
                float4 kv = kr[u];
                a0 += q[u].x * kv.x; a1 += q[u].y * kv.y;
                a2 += q[u].z * kv.z; a3 += q[u].w * kv.w;
            }
            float sv = (a0 + a1) + (a2 + a3);
            s[jj] = (jc + jj <= i) ? sv * 0.125f : -1e30f;
        }
        float mc = s[0];
#pragma unroll
        for (int jj = 1; jj < 8; jj++) mc = fmaxf(mc, s[jj]);
        float mnew  = fmaxf(m, mc);
        float scale = __expf(m - mnew);
        float p[8];
        float psum = 0.f;
#pragma unroll
        for (int jj = 0; jj < 8; jj++) { p[jj] = __expf(s[jj] - mnew); psum += p[jj]; }
        m = mnew;
        l = l * scale + psum;
#pragma unroll
        for (int u = 0; u < 16; u++) {
            o[u].x *= scale; o[u].y *= scale; o[u].z *= scale; o[u].w *= scale;
        }
#pragma unroll
        for (int jj = 0; jj < 8; jj++) {
            const float4* vr = (const float4*)(Vp + (size_t)(jc + jj) * 64);
            float pj = p[jj];
#pragma unroll
            for (int u = 0; u < 16; u++) {
                float4 vv = vr[u];
                o[u].x += pj * vv.x; o[u].y += pj * vv.y;
                o[u].z += pj * vv.z; o[u].w += pj * vv.w;
            }
        }
    }

    float inv = 1.f / l;
    // write bf16 to [b][t][h][d] so the out-projection GEMM reads it row-major
    size_t dst = ((size_t)(b * TT + i) * NHEADS + h) * 64;
#pragma unroll
    for (int u = 0; u < 16; u++) {
        ushort4 pk;
        pk.x = f2bf(o[u].x * inv); pk.y = f2bf(o[u].y * inv);
        pk.z = f2bf(o[u].z * inv); pk.w = f2bf(o[u].w * inv);
        *(ushort4*)(out + dst + u * 4) = pk;
    }
}

// ---------- launch ----------
extern "C" void kernel_launch(void* const* d_in, const int* in_sizes, int n_in,
                              void* d_out, int out_size, void* d_ws, size_t ws_size,
                              hipStream_t stream) {
    const float* x     = (const float*)d_in[0];   // [2,2048,1024]
    const float* w_qkv = (const float*)d_in[1];   // [3072,1024]
    const float* w_out = (const float*)d_in[2];   // [1024,1024]
    float* out = (float*)d_out;                   // [2,2048,1024]

    char* ws = (char*)d_ws;
    const size_t N_X   = (size_t)BB * TT * DMODEL;        // 4,194,304
    const size_t N_WQ  = (size_t)3 * DMODEL * DMODEL;     // 3,145,728
    const size_t N_WO  = (size_t)DMODEL * DMODEL;         // 1,048,576

    unsigned short* xb   = (unsigned short*)(ws);                       // 8,388,608 B
    unsigned short* wqb  = (unsigned short*)(ws + 8388608);             // 6,291,456 B
    unsigned short* wob  = (unsigned short*)(ws + 14680064);            // 2,097,152 B
    float*          qkv  = (float*)(ws + 16777216);                     // 50,331,648 B
    float*          qTp  = (float*)(ws + 67108864);                     // 16,777,216 B
    float*          kTp  = (float*)(ws + 83886080);                     // 16,777,216 B
    float*          vTp  = (float*)(ws + 100663296);                    // 16,777,216 B
    unsigned short* attb = (unsigned short*)(ws + 117440512);           // 8,388,608 B

    castk<<<N_X  / 1024, 256, 0, stream>>>(x,     xb,  (int)N_X);
    castk<<<N_WQ / 1024, 256, 0, stream>>>(w_qkv, wqb, (int)N_WQ);
    castk<<<N_WO / 1024, 256, 0, stream>>>(w_out, wob, (int)N_WO);

    // qkv = x @ w_qkv^T   (M=4096, N=3072, K=1024)
    gemm_bt<<<dim3(3072 / 128, 4096 / 128), 256, 0, stream>>>(xb, wqb, qkv, 4096, 3072, 1024);

    rope_split<<<(BB * TT * NHEADS * 32) / 256, 256, 0, stream>>>(qkv, qTp, kTp, vTp);

    attn_fp32<<<dim3(TT / 64, BB * NHEADS), 64, 0, stream>>>(qTp, kTp, vTp, attb);

    // out = attn @ w_out^T (M=4096, N=1024, K=1024)
    gemm_bt<<<dim3(1024 / 128, 4096 / 128), 256, 0, stream>>>(attb, wob, out, 4096, 1024, 1024);
}

// Round 3
// 311.856 us; speedup vs baseline: 12.8268x; 12.8268x over previous
//
#include <hip/hip_runtime.h>
#include <cstdint>
#include <cstddef>

// Problem constants
#define BB 2
#define TT 2048
#define DMODEL 1024
#define NHEADS 16
#define DK 64

typedef short short8 __attribute__((ext_vector_type(8)));
typedef unsigned short ushort8 __attribute__((ext_vector_type(8)));
typedef float floatx4 __attribute__((ext_vector_type(4)));

// ---------- helpers ----------
__device__ __forceinline__ unsigned short f2bf(float f) {
    uint32_t u = __builtin_bit_cast(uint32_t, f);
    uint32_t r = (u + 0x7FFFu + ((u >> 16) & 1u)) >> 16;
    return (unsigned short)r;
}

#define GLDS16(g, l) __builtin_amdgcn_global_load_lds( \
    (const __attribute__((address_space(1))) void*)(g), \
    (__attribute__((address_space(3))) void*)(l), 16, 0, 0)

// ---------- cast fp32 -> bf16 (vector x4) ----------
__global__ void castk(const float* __restrict__ in, unsigned short* __restrict__ out, int n) {
    int i = (blockIdx.x * blockDim.x + threadIdx.x) * 4;
    if (i >= n) return;
    float4 v = *(const float4*)(in + i);
    ushort4 o;
    o.x = f2bf(v.x); o.y = f2bf(v.y); o.z = f2bf(v.z); o.w = f2bf(v.w);
    *(ushort4*)(out + i) = o;
}

// ---------- bf16 MFMA GEMM, C = A * B^T  (A: [M][K], B: [N][K], C fp32 [M][N]) ----------
__global__ __launch_bounds__(256)
void gemm_bt(const unsigned short* __restrict__ A, const unsigned short* __restrict__ B,
             float* __restrict__ C, int M, int N, int K) {
    __shared__ unsigned short As[128 * 32];
    __shared__ unsigned short Bs[128 * 32];

    const int tid  = threadIdx.x;
    const int lane = tid & 63;
    const int w    = tid >> 6;
    const int wm   = w & 1;
    const int wn   = w >> 1;
    const int quad = lane >> 4;
    const int l16  = lane & 15;

    const int m0 = blockIdx.y * 128;
    const int n0 = blockIdx.x * 128;

    floatx4 acc[4][4];
#pragma unroll
    for (int a = 0; a < 4; a++)
#pragma unroll
        for (int b = 0; b < 4; b++)
            acc[a][b] = (floatx4){0.f, 0.f, 0.f, 0.f};

    const int c0 = w * 128 + lane;
    const int c1 = c0 + 64;
    const int r0 = c0 >> 2, cc0 = c0 & 3;
    const int r1 = c1 >> 2, cc1 = c1 & 3;

    const unsigned short* gA0 = A + (size_t)(m0 + r0) * K + cc0 * 8;
    const unsigned short* gA1 = A + (size_t)(m0 + r1) * K + cc1 * 8;
    const unsigned short* gB0 = B + (size_t)(n0 + r0) * K + cc0 * 8;
    const unsigned short* gB1 = B + (size_t)(n0 + r1) * K + cc1 * 8;

    unsigned short* lA0 = &As[(2 * w + 0) * 512];
    unsigned short* lA1 = &As[(2 * w + 1) * 512];
    unsigned short* lB0 = &Bs[(2 * w + 0) * 512];
    unsigned short* lB1 = &Bs[(2 * w + 1) * 512];

    for (int k0 = 0; k0 < K; k0 += 32) {
        __syncthreads();
        GLDS16(gA0 + k0, lA0);
        GLDS16(gA1 + k0, lA1);
        GLDS16(gB0 + k0, lB0);
        GLDS16(gB1 + k0, lB1);
        __syncthreads();

        short8 af[4], bf[4];
#pragma unroll
        for (int t = 0; t < 4; t++) {
            af[t] = *(const short8*)&As[(wm * 64 + t * 16 + l16) * 32 + quad * 8];
            bf[t] = *(const short8*)&Bs[(wn * 64 + t * 16 + l16) * 32 + quad * 8];
        }
#pragma unroll
        for (int tm = 0; tm < 4; tm++)
#pragma unroll
            for (int tn = 0; tn < 4; tn++)
                acc[tm][tn] = __builtin_amdgcn_mfma_f32_16x16x32_bf16(
                    af[tm], bf[tn], acc[tm][tn], 0, 0, 0);
    }

#pragma unroll
    for (int tm = 0; tm < 4; tm++) {
#pragma unroll
        for (int tn = 0; tn < 4; tn++) {
#pragma unroll
            for (int r = 0; r < 4; r++) {
                int m = m0 + wm * 64 + tm * 16 + quad * 4 + r;
                int n = n0 + wn * 64 + tn * 16 + l16;
                C[(size_t)m * N + n] = acc[tm][tn][r];
            }
        }
    }
}

// ---------- RoPE + split: qkv fp32 [B*T][3072] -> qb,kb bf16 [B*H][T][64] ----------
__global__ void rope_split(const float* __restrict__ qkv,
                           unsigned short* __restrict__ qb, unsigned short* __restrict__ kb) {
    int idx = blockIdx.x * blockDim.x + threadIdx.x;
    int p = idx & 31;
    int h = (idx >> 5) & 15;
    int t = (idx >> 9) & 2047;
    int b = idx >> 20;

    size_t src = (size_t)(b * TT + t) * 3072 + h * 64 + 2 * p;
    float2 q = *(const float2*)(qkv + src);
    float2 k = *(const float2*)(qkv + src + 1024);

    float invf = __powf(10000.f, -((float)(2 * p)) / 64.f);
    float ang  = (float)t * invf;
    float sn, cs;
    __sincosf(ang, &sn, &cs);

    size_t dst = ((size_t)(b * NHEADS + h) * TT + t) * 64 + 2 * p;
    ushort2 qo, ko;
    qo.x = f2bf(q.x * cs - q.y * sn); qo.y = f2bf(q.y * cs + q.x * sn);
    ko.x = f2bf(k.x * cs - k.y * sn); ko.y = f2bf(k.y * cs + k.x * sn);
    *(ushort2*)(qb + dst) = qo;
    *(ushort2*)(kb + dst) = ko;
}

// ---------- V transpose: qkv fp32 v-slice -> vtb bf16 [B*H][64][T] ----------
__global__ __launch_bounds__(256)
void vtrans(const float* __restrict__ qkv, unsigned short* __restrict__ vtb) {
    __shared__ float tile[64][65];
    const int tid = threadIdx.x;
    const int bh = blockIdx.y;
    const int b = bh >> 4, h = bh & 15;
    const int t0 = blockIdx.x * 64;

    // load 64t x 64d fp32: each thread loads 4 float4s (row = tid>>2)
    const int row = tid >> 2;
    const float* src = qkv + ((size_t)(b * TT) + t0 + row) * 3072 + 2048 + h * 64;
#pragma unroll
    for (int i = 0; i < 4; i++) {
        int c4 = (tid & 3) * 4 + i;   // 0..15
        float4 v = *(const float4*)(src + c4 * 4);
        tile[row][c4 * 4 + 0] = v.x;
        tile[row][c4 * 4 + 1] = v.y;
        tile[row][c4 * 4 + 2] = v.z;
        tile[row][c4 * 4 + 3] = v.w;
    }
    __syncthreads();

    // write transposed: thread handles d = tid>>2, 16 t-values
    const int d  = tid >> 2;
    const int tc = tid & 3;
    ushort8 o0, o1;
#pragma unroll
    for (int i = 0; i < 8; i++) o0[i] = f2bf(tile[tc * 16 + i][d]);
#pragma unroll
    for (int i = 0; i < 8; i++) o1[i] = f2bf(tile[tc * 16 + 8 + i][d]);
    unsigned short* dst = vtb + ((size_t)bh * 64 + d) * TT + t0 + tc * 16;
    *(ushort8*)(dst) = o0;
    *(ushort8*)(dst + 8) = o1;
}

// ---------- MFMA flash attention (causal), bf16 in, bf16 out ----------
// block = 4 waves; wave w computes q-rows [q0 + w*16, +16); KV tiles of 64.
__global__ __launch_bounds__(256)
void attn_mfma(const unsigned short* __restrict__ qb,
               const unsigned short* __restrict__ kb,
               const unsigned short* __restrict__ vtb,
               unsigned short* __restrict__ out) {
    __shared__ unsigned short Ks[64 * 64];    // [t][d]
    __shared__ unsigned short VTs[64 * 64];   // [d][t]
    __shared__ unsigned short Ps[64 * 72];    // [qrow][t], stride 72 el = 144 B (16B-aligned)

    const int tid  = threadIdx.x;
    const int lane = tid & 63;
    const int w    = tid >> 6;
    const int quad = lane >> 4;
    const int l16  = lane & 15;

    const int bh    = blockIdx.y;
    const int qtile = gridDim.x - 1 - blockIdx.x;   // longest blocks dispatch first
    const int q0    = qtile * 64;

    const unsigned short* Qp = qb + ((size_t)bh * TT + q0) * 64;
    const unsigned short* Kp = kb + (size_t)bh * TT * 64;
    const unsigned short* Vp = vtb + (size_t)bh * 64 * TT;

    // Q fragments (A-operand: m=l16 wave-local q-row, k=ks*32+quad*8+j)
    short8 aq[2];
#pragma unroll
    for (int ks = 0; ks < 2; ks++)
        aq[ks] = *(const short8*)(Qp + (size_t)(w * 16 + l16) * 64 + ks * 32 + quad * 8);

    floatx4 Oacc[4];
#pragma unroll
    for (int dt = 0; dt < 4; dt++) Oacc[dt] = (floatx4){0.f, 0.f, 0.f, 0.f};
    float mrow[4] = {-1e30f, -1e30f, -1e30f, -1e30f};
    float lrow[4] = {0.f, 0.f, 0.f, 0.f};

    const int ntiles = qtile + 1;
    for (int it = 0; it < ntiles; ++it) {
        const int j0 = it * 64;
        __syncthreads();
        // stage K tile + VT tile: each 64x64 bf16 = 512 chunks of 16B (8 el/row-chunk, 8 chunks/row)
#pragma unroll
        for (int it2 = 0; it2 < 2; it2++) {
            int c = it2 * 256 + w * 64 + lane;          // 0..511
            int t = c >> 3, dc = c & 7;
            GLDS16(Kp + (size_t)(j0 + t) * 64 + dc * 8, &Ks[(it2 * 256 + w * 64) * 8]);
            int d = c >> 3, tc = c & 7;
            GLDS16(Vp + (size_t)d * TT + j0 + tc * 8, &VTs[(it2 * 256 + w * 64) * 8]);
        }
        __syncthreads();

        // S = Q K^T (wave-local 16x64)
        floatx4 sacc[4];
#pragma unroll
        for (int nt = 0; nt < 4; nt++) sacc[nt] = (floatx4){0.f, 0.f, 0.f, 0.f};
#pragma unroll
        for (int ks = 0; ks < 2; ks++)
#pragma unroll
            for (int nt = 0; nt < 4; nt++) {
                short8 bk = *(const short8*)&Ks[(nt * 16 + l16) * 64 + ks * 32 + quad * 8];
                sacc[nt] = __builtin_amdgcn_mfma_f32_16x16x32_bf16(aq[ks], bk, sacc[nt], 0, 0, 0);
            }

        // scale + causal mask (only diagonal tile needs masking)
        float s[4][4];
        const bool diag = (it == qtile);
#pragma unroll
        for (int nt = 0; nt < 4; nt++)
#pragma unroll
            for (int r = 0; r < 4; r++) {
                float sv = sacc[nt][r] * 0.125f;
                if (diag && (nt * 16 + l16 > w * 16 + quad * 4 + r)) sv = -1e30f;
                s[nt][r] = sv;
            }

        // online softmax per q-row (row = quad*4+r; 16 lanes of this quad share it)
        float alpha[4];
#pragma unroll
        for (int r = 0; r < 4; r++) {
            float mx = fmaxf(fmaxf(s[0][r], s[1][r]), fmaxf(s[2][r], s[3][r]));
            mx = fmaxf(mx, __shfl_xor(mx, 1));
            mx = fmaxf(mx, __shfl_xor(mx, 2));
            mx = fmaxf(mx, __shfl_xor(mx, 4));
            mx = fmaxf(mx, __shfl_xor(mx, 8));
            float mnew = fmaxf(mrow[r], mx);
            alpha[r] = __expf(mrow[r] - mnew);
            mrow[r] = mnew;
            float psum = 0.f;
#pragma unroll
            for (int nt = 0; nt < 4; nt++) {
                float p = __expf(s[nt][r] - mnew);
                s[nt][r] = p;
                psum += p;
            }
            psum += __shfl_xor(psum, 1);
            psum += __shfl_xor(psum, 2);
            psum += __shfl_xor(psum, 4);
            psum += __shfl_xor(psum, 8);
            lrow[r] = lrow[r] * alpha[r] + psum;
        }

        // rescale O accumulators
#pragma unroll
        for (int dt = 0; dt < 4; dt++)
#pragma unroll
            for (int r = 0; r < 4; r++) Oacc[dt][r] *= alpha[r];

        // P (C/D layout) -> LDS -> A-operand layout. Per-wave region; no barrier needed.
#pragma unroll
        for (int nt = 0; nt < 4; nt++)
#pragma unroll
            for (int r = 0; r < 4; r++)
                Ps[(w * 16 + quad * 4 + r) * 72 + nt * 16 + l16] = f2bf(s[nt][r]);

        short8 ap[2];
#pragma unroll
        for (int ks = 0; ks < 2; ks++)
            ap[ks] = *(const short8*)&Ps[(w * 16 + l16) * 72 + ks * 32 + quad * 8];

        // O += P V  (B-operand: n=d=dt*16+l16, k=t from VTs[d][t])
#pragma unroll
        for (int ks = 0; ks < 2; ks++)
#pragma unroll
            for (int dt = 0; dt < 4; dt++) {
                short8 bv = *(const short8*)&VTs[(dt * 16 + l16) * 64 + ks * 32 + quad * 8];
                Oacc[dt] = __builtin_amdgcn_mfma_f32_16x16x32_bf16(ap[ks], bv, Oacc[dt], 0, 0, 0);
            }
    }

    // epilogue: out[b][t][h*64+d] bf16
    const int b = bh >> 4, h = bh & 15;
#pragma unroll
    for (int r = 0; r < 4; r++) {
        float inv = 1.f / lrow[r];
        int t = q0 + w * 16 + quad * 4 + r;
        size_t base = ((size_t)(b * TT + t)) * DMODEL + h * 64;
#pragma unroll
        for (int dt = 0; dt < 4; dt++)
            out[base + dt * 16 + l16] = f2bf(Oacc[dt][r] * inv);
    }
}

// ---------- launch ----------
extern "C" void kernel_launch(void* const* d_in, const int* in_sizes, int n_in,
                              void* d_out, int out_size, void* d_ws, size_t ws_size,
                              hipStream_t stream) {
    const float* x     = (const float*)d_in[0];   // [2,2048,1024]
    const float* w_qkv = (const float*)d_in[1];   // [3072,1024]
    const float* w_out = (const float*)d_in[2];   // [1024,1024]
    float* out = (float*)d_out;                   // [2,2048,1024]

    char* ws = (char*)d_ws;
    const size_t N_X  = (size_t)BB * TT * DMODEL;     // 4,194,304
    const size_t N_WQ = (size_t)3 * DMODEL * DMODEL;  // 3,145,728
    const size_t N_WO = (size_t)DMODEL * DMODEL;      // 1,048,576

    unsigned short* xb   = (unsigned short*)(ws);                 // 8 MB
    unsigned short* wqb  = (unsigned short*)(ws + 8388608);       // 6 MB
    unsigned short* wob  = (unsigned short*)(ws + 14680064);      // 2 MB
    float*          qkv  = (float*)(ws + 16777216);               // 48 MB
    unsigned short* qb   = (unsigned short*)(ws + 67108864);      // 8 MB
    unsigned short* kb   = (unsigned short*)(ws + 75497472);      // 8 MB
    unsigned short* vtb  = (unsigned short*)(ws + 83886080);      // 8 MB
    unsigned short* attb = (unsigned short*)(ws + 92274688);      // 8 MB

    castk<<<N_X  / 1024, 256, 0, stream>>>(x,     xb,  (int)N_X);
    castk<<<N_WQ / 1024, 256, 0, stream>>>(w_qkv, wqb, (int)N_WQ);
    castk<<<N_WO / 1024, 256, 0, stream>>>(w_out, wob, (int)N_WO);

    // qkv = x @ w_qkv^T   (M=4096, N=3072, K=1024)
    gemm_bt<<<dim3(3072 / 128, 4096 / 128), 256, 0, stream>>>(xb, wqb, qkv, 4096, 3072, 1024);

    rope_split<<<(BB * TT * NHEADS * 32) / 256, 256, 0, stream>>>(qkv, qb, kb);
    vtrans<<<dim3(TT / 64, BB * NHEADS), 256, 0, stream>>>(qkv, vtb);

    attn_mfma<<<dim3(TT / 64, BB * NHEADS), 256, 0, stream>>>(qb, kb, vtb, attb);

    // out = attn @ w_out^T (M=4096, N=1024, K=1024)
    gemm_bt<<<dim3(1024 / 128, 4096 / 128), 256, 0, stream>>>(attb, wob, out, 4096, 1024, 1024);
}

// Round 4
// 287.179 us; speedup vs baseline: 13.9291x; 1.0859x over previous
//
#include <hip/hip_runtime.h>
#include <cstdint>
#include <cstddef>

// Problem constants
#define BB 2
#define TT 2048
#define DMODEL 1024
#define NHEADS 16
#define DK 64

typedef short short8 __attribute__((ext_vector_type(8)));
typedef unsigned short ushort8 __attribute__((ext_vector_type(8)));
typedef float floatx4 __attribute__((ext_vector_type(4)));

// ---------- helpers ----------
__device__ __forceinline__ unsigned short f2bf(float f) {
    uint32_t u = __builtin_bit_cast(uint32_t, f);
    uint32_t r = (u + 0x7FFFu + ((u >> 16) & 1u)) >> 16;
    return (unsigned short)r;
}

#define GLDS16(g, l) __builtin_amdgcn_global_load_lds( \
    (const __attribute__((address_space(1))) void*)(g), \
    (__attribute__((address_space(3))) void*)(l), 16, 0, 0)

// ---------- cast fp32 -> bf16 (vector x4) ----------
__global__ void castk(const float* __restrict__ in, unsigned short* __restrict__ out, int n) {
    int i = (blockIdx.x * blockDim.x + threadIdx.x) * 4;
    if (i >= n) return;
    float4 v = *(const float4*)(in + i);
    ushort4 o;
    o.x = f2bf(v.x); o.y = f2bf(v.y); o.z = f2bf(v.z); o.w = f2bf(v.w);
    *(ushort4*)(out + i) = o;
}

// ---------- bf16 MFMA GEMM, C = A * B^T  (A: [M][K], B: [N][K], C fp32 [M][N]) ----------
// XOR-swizzled LDS staging: row chunk cc stored at slot cc ^ ((row>>1)&3).
__global__ __launch_bounds__(256)
void gemm_bt(const unsigned short* __restrict__ A, const unsigned short* __restrict__ B,
             float* __restrict__ C, int M, int N, int K) {
    __shared__ unsigned short As[128 * 32];
    __shared__ unsigned short Bs[128 * 32];

    const int tid  = threadIdx.x;
    const int lane = tid & 63;
    const int w    = tid >> 6;
    const int wm   = w & 1;
    const int wn   = w >> 1;
    const int quad = lane >> 4;
    const int l16  = lane & 15;

    const int m0 = blockIdx.y * 128;
    const int n0 = blockIdx.x * 128;

    floatx4 acc[4][4];
#pragma unroll
    for (int a = 0; a < 4; a++)
#pragma unroll
        for (int b = 0; b < 4; b++)
            acc[a][b] = (floatx4){0.f, 0.f, 0.f, 0.f};

    const int c0 = w * 128 + lane;
    const int c1 = c0 + 64;
    const int r0 = c0 >> 2, cc0 = (c0 & 3) ^ ((r0 >> 1) & 3);
    const int r1 = c1 >> 2, cc1 = (c1 & 3) ^ ((r1 >> 1) & 3);

    const unsigned short* gA0 = A + (size_t)(m0 + r0) * K + cc0 * 8;
    const unsigned short* gA1 = A + (size_t)(m0 + r1) * K + cc1 * 8;
    const unsigned short* gB0 = B + (size_t)(n0 + r0) * K + cc0 * 8;
    const unsigned short* gB1 = B + (size_t)(n0 + r1) * K + cc1 * 8;

    unsigned short* lA0 = &As[(2 * w + 0) * 512];
    unsigned short* lA1 = &As[(2 * w + 1) * 512];
    unsigned short* lB0 = &Bs[(2 * w + 0) * 512];
    unsigned short* lB1 = &Bs[(2 * w + 1) * 512];

    const int rsw = (l16 >> 1) & 3;   // (row>>1)&3 for all fragment rows this lane reads

    for (int k0 = 0; k0 < K; k0 += 32) {
        __syncthreads();
        GLDS16(gA0 + k0, lA0);
        GLDS16(gA1 + k0, lA1);
        GLDS16(gB0 + k0, lB0);
        GLDS16(gB1 + k0, lB1);
        __syncthreads();

        short8 af[4], bf[4];
#pragma unroll
        for (int t = 0; t < 4; t++) {
            af[t] = *(const short8*)&As[(wm * 64 + t * 16 + l16) * 32 + (quad ^ rsw) * 8];
            bf[t] = *(const short8*)&Bs[(wn * 64 + t * 16 + l16) * 32 + (quad ^ rsw) * 8];
        }
#pragma unroll
        for (int tm = 0; tm < 4; tm++)
#pragma unroll
            for (int tn = 0; tn < 4; tn++)
                acc[tm][tn] = __builtin_amdgcn_mfma_f32_16x16x32_bf16(
                    af[tm], bf[tn], acc[tm][tn], 0, 0, 0);
    }

#pragma unroll
    for (int tm = 0; tm < 4; tm++) {
#pragma unroll
        for (int tn = 0; tn < 4; tn++) {
#pragma unroll
            for (int r = 0; r < 4; r++) {
                int m = m0 + wm * 64 + tm * 16 + quad * 4 + r;
                int n = n0 + wn * 64 + tn * 16 + l16;
                C[(size_t)m * N + n] = acc[tm][tn][r];
            }
        }
    }
}

// ---------- RoPE + split: qkv fp32 [B*T][3072] -> qb,kb bf16 [B*H][T][64] ----------
__global__ void rope_split(const float* __restrict__ qkv,
                           unsigned short* __restrict__ qb, unsigned short* __restrict__ kb) {
    int idx = blockIdx.x * blockDim.x + threadIdx.x;
    int p = idx & 31;
    int h = (idx >> 5) & 15;
    int t = (idx >> 9) & 2047;
    int b = idx >> 20;

    size_t src = (size_t)(b * TT + t) * 3072 + h * 64 + 2 * p;
    float2 q = *(const float2*)(qkv + src);
    float2 k = *(const float2*)(qkv + src + 1024);

    float invf = __powf(10000.f, -((float)(2 * p)) / 64.f);
    float ang  = (float)t * invf;
    float sn, cs;
    __sincosf(ang, &sn, &cs);

    size_t dst = ((size_t)(b * NHEADS + h) * TT + t) * 64 + 2 * p;
    ushort2 qo, ko;
    qo.x = f2bf(q.x * cs - q.y * sn); qo.y = f2bf(q.y * cs + q.x * sn);
    ko.x = f2bf(k.x * cs - k.y * sn); ko.y = f2bf(k.y * cs + k.x * sn);
    *(ushort2*)(qb + dst) = qo;
    *(ushort2*)(kb + dst) = ko;
}

// ---------- V transpose: qkv fp32 v-slice -> vtb bf16 [B*H][64][T] ----------
__global__ __launch_bounds__(256)
void vtrans(const float* __restrict__ qkv, unsigned short* __restrict__ vtb) {
    __shared__ float tile[64][65];
    const int tid = threadIdx.x;
    const int bh = blockIdx.y;
    const int b = bh >> 4, h = bh & 15;
    const int t0 = blockIdx.x * 64;

    const int row = tid >> 2;
    const float* src = qkv + ((size_t)(b * TT) + t0 + row) * 3072 + 2048 + h * 64;
#pragma unroll
    for (int i = 0; i < 4; i++) {
        int c4 = (tid & 3) * 4 + i;   // 0..15
        float4 v = *(const float4*)(src + c4 * 4);
        tile[row][c4 * 4 + 0] = v.x;
        tile[row][c4 * 4 + 1] = v.y;
        tile[row][c4 * 4 + 2] = v.z;
        tile[row][c4 * 4 + 3] = v.w;
    }
    __syncthreads();

    const int d  = tid >> 2;
    const int tc = tid & 3;
    ushort8 o0, o1;
#pragma unroll
    for (int i = 0; i < 8; i++) o0[i] = f2bf(tile[tc * 16 + i][d]);
#pragma unroll
    for (int i = 0; i < 8; i++) o1[i] = f2bf(tile[tc * 16 + 8 + i][d]);
    unsigned short* dst = vtb + ((size_t)bh * 64 + d) * TT + t0 + tc * 16;
    *(ushort8*)(dst) = o0;
    *(ushort8*)(dst + 8) = o1;
}

// ---------- MFMA flash attention (causal), bf16 in, bf16 out ----------
// block = 4 waves; wave w computes q-rows [q0 + w*16, +16); KV tiles of 64.
// Ks/VTs staging XOR-swizzled: row chunk dc at slot dc ^ (row&7).
__global__ __launch_bounds__(256)
void attn_mfma(const unsigned short* __restrict__ qb,
               const unsigned short* __restrict__ kb,
               const unsigned short* __restrict__ vtb,
               unsigned short* __restrict__ out) {
    __shared__ unsigned short Ks[64 * 64];    // [t][d] (chunk-swizzled)
    __shared__ unsigned short VTs[64 * 64];   // [d][t] (chunk-swizzled)
    __shared__ unsigned short Ps[64 * 68];    // [qrow][t], stride 68 el = 136 B

    const int tid  = threadIdx.x;
    const int lane = tid & 63;
    const int w    = tid >> 6;
    const int quad = lane >> 4;
    const int l16  = lane & 15;

    const int bh    = blockIdx.y;
    const int qtile = gridDim.x - 1 - blockIdx.x;   // longest blocks dispatch first
    const int q0    = qtile * 64;

    const unsigned short* Qp = qb + ((size_t)bh * TT + q0) * 64;
    const unsigned short* Kp = kb + (size_t)bh * TT * 64;
    const unsigned short* Vp = vtb + (size_t)bh * 64 * TT;

    // Q fragments (A-operand: m=l16 wave-local q-row, k=ks*32+quad*8+j)
    short8 aq[2];
#pragma unroll
    for (int ks = 0; ks < 2; ks++)
        aq[ks] = *(const short8*)(Qp + (size_t)(w * 16 + l16) * 64 + ks * 32 + quad * 8);

    floatx4 Oacc[4];
#pragma unroll
    for (int dt = 0; dt < 4; dt++) Oacc[dt] = (floatx4){0.f, 0.f, 0.f, 0.f};
    float mrow[4] = {-1e30f, -1e30f, -1e30f, -1e30f};
    float lrow[4] = {0.f, 0.f, 0.f, 0.f};

    const int sw = l16 & 7;   // row&7 for all fragment rows this lane reads

    // staging indices (computed once)
    const int ntiles = qtile + 1;
    for (int it = 0; it < ntiles; ++it) {
        const int j0 = it * 64;
        __syncthreads();
        // stage K tile + VT tile: 64x64 bf16 = 512 chunks of 16B each (8 chunks/row)
#pragma unroll
        for (int it2 = 0; it2 < 2; it2++) {
            int c = it2 * 256 + w * 64 + lane;          // 0..511
            int t = c >> 3, dc = c & 7;
            int dcs = dc ^ (t & 7);
            GLDS16(Kp + (size_t)(j0 + t) * 64 + dcs * 8, &Ks[(it2 * 256 + w * 64) * 8]);
            GLDS16(Vp + (size_t)t * TT + j0 + dcs * 8, &VTs[(it2 * 256 + w * 64) * 8]);
        }
        __syncthreads();

        // S = Q K^T (wave-local 16x64)
        floatx4 sacc[4];
#pragma unroll
        for (int nt = 0; nt < 4; nt++) sacc[nt] = (floatx4){0.f, 0.f, 0.f, 0.f};
#pragma unroll
        for (int ks = 0; ks < 2; ks++)
#pragma unroll
            for (int nt = 0; nt < 4; nt++) {
                short8 bk = *(const short8*)&Ks[(nt * 16 + l16) * 64 + ((ks * 4 + quad) ^ sw) * 8];
                sacc[nt] = __builtin_amdgcn_mfma_f32_16x16x32_bf16(aq[ks], bk, sacc[nt], 0, 0, 0);
            }

        // scale + causal mask (only diagonal tile needs masking)
        float s[4][4];
        const bool diag = (it == qtile);
#pragma unroll
        for (int nt = 0; nt < 4; nt++)
#pragma unroll
            for (int r = 0; r < 4; r++) {
                float sv = sacc[nt][r] * 0.125f;
                if (diag && (nt * 16 + l16 > w * 16 + quad * 4 + r)) sv = -1e30f;
                s[nt][r] = sv;
            }

        // online softmax per q-row (row = quad*4+r; 16 lanes of this quad share it)
        float alpha[4];
#pragma unroll
        for (int r = 0; r < 4; r++) {
            float mx = fmaxf(fmaxf(s[0][r], s[1][r]), fmaxf(s[2][r], s[3][r]));
            mx = fmaxf(mx, __shfl_xor(mx, 1));
            mx = fmaxf(mx, __shfl_xor(mx, 2));
            mx = fmaxf(mx, __shfl_xor(mx, 4));
            mx = fmaxf(mx, __shfl_xor(mx, 8));
            float mnew = fmaxf(mrow[r], mx);
            alpha[r] = __expf(mrow[r] - mnew);
            mrow[r] = mnew;
            float psum = 0.f;
#pragma unroll
            for (int nt = 0; nt < 4; nt++) {
                float p = __expf(s[nt][r] - mnew);
                s[nt][r] = p;
                psum += p;
            }
            psum += __shfl_xor(psum, 1);
            psum += __shfl_xor(psum, 2);
            psum += __shfl_xor(psum, 4);
            psum += __shfl_xor(psum, 8);
            lrow[r] = lrow[r] * alpha[r] + psum;
        }

        // rescale O accumulators
#pragma unroll
        for (int dt = 0; dt < 4; dt++)
#pragma unroll
            for (int r = 0; r < 4; r++) Oacc[dt][r] *= alpha[r];

        // P (C/D layout) -> LDS -> A-operand layout. Per-wave region; no barrier needed.
#pragma unroll
        for (int nt = 0; nt < 4; nt++)
#pragma unroll
            for (int r = 0; r < 4; r++)
                Ps[(w * 16 + quad * 4 + r) * 68 + nt * 16 + l16] = f2bf(s[nt][r]);

        short8 ap[2];
#pragma unroll
        for (int ks = 0; ks < 2; ks++) {
            ushort4 lo = *(const ushort4*)&Ps[(w * 16 + l16) * 68 + ks * 32 + quad * 8];
            ushort4 hi = *(const ushort4*)&Ps[(w * 16 + l16) * 68 + ks * 32 + quad * 8 + 4];
            short8 t;
            t[0] = lo.x; t[1] = lo.y; t[2] = lo.z; t[3] = lo.w;
            t[4] = hi.x; t[5] = hi.y; t[6] = hi.z; t[7] = hi.w;
            ap[ks] = t;
        }

        // O += P V  (B-operand: n=d=dt*16+l16, k=t from VTs[d][t])
#pragma unroll
        for (int ks = 0; ks < 2; ks++)
#pragma unroll
            for (int dt = 0; dt < 4; dt++) {
                short8 bv = *(const short8*)&VTs[(dt * 16 + l16) * 64 + ((ks * 4 + quad) ^ sw) * 8];
                Oacc[dt] = __builtin_amdgcn_mfma_f32_16x16x32_bf16(ap[ks], bv, Oacc[dt], 0, 0, 0);
            }
    }

    // epilogue: out[b][t][h*64+d] bf16
    const int b = bh >> 4, h = bh & 15;
#pragma unroll
    for (int r = 0; r < 4; r++) {
        float inv = 1.f / lrow[r];
        int t = q0 + w * 16 + quad * 4 + r;
        size_t base = ((size_t)(b * TT + t)) * DMODEL + h * 64;
#pragma unroll
        for (int dt = 0; dt < 4; dt++)
            out[base + dt * 16 + l16] = f2bf(Oacc[dt][r] * inv);
    }
}

// ---------- launch ----------
extern "C" void kernel_launch(void* const* d_in, const int* in_sizes, int n_in,
                              void* d_out, int out_size, void* d_ws, size_t ws_size,
                              hipStream_t stream) {
    const float* x     = (const float*)d_in[0];   // [2,2048,1024]
    const float* w_qkv = (const float*)d_in[1];   // [3072,1024]
    const float* w_out = (const float*)d_in[2];   // [1024,1024]
    float* out = (float*)d_out;                   // [2,2048,1024]

    char* ws = (char*)d_ws;
    const size_t N_X  = (size_t)BB * TT * DMODEL;     // 4,194,304
    const size_t N_WQ = (size_t)3 * DMODEL * DMODEL;  // 3,145,728
    const size_t N_WO = (size_t)DMODEL * DMODEL;      // 1,048,576

    unsigned short* xb   = (unsigned short*)(ws);                 // 8 MB
    unsigned short* wqb  = (unsigned short*)(ws + 8388608);       // 6 MB
    unsigned short* wob  = (unsigned short*)(ws + 14680064);      // 2 MB
    float*          qkv  = (float*)(ws + 16777216);               // 48 MB
    unsigned short* qb   = (unsigned short*)(ws + 67108864);      // 8 MB
    unsigned short* kb   = (unsigned short*)(ws + 75497472);      // 8 MB
    unsigned short* vtb  = (unsigned short*)(ws + 83886080);      // 8 MB
    unsigned short* attb = (unsigned short*)(ws + 92274688);      // 8 MB

    castk<<<N_X  / 1024, 256, 0, stream>>>(x,     xb,  (int)N_X);
    castk<<<N_WQ / 1024, 256, 0, stream>>>(w_qkv, wqb, (int)N_WQ);
    castk<<<N_WO / 1024, 256, 0, stream>>>(w_out, wob, (int)N_WO);

    // qkv = x @ w_qkv^T   (M=4096, N=3072, K=1024)
    gemm_bt<<<dim3(3072 / 128, 4096 / 128), 256, 0, stream>>>(xb, wqb, qkv, 4096, 3072, 1024);

    rope_split<<<(BB * TT * NHEADS * 32) / 256, 256, 0, stream>>>(qkv, qb, kb);
    vtrans<<<dim3(TT / 64, BB * NHEADS), 256, 0, stream>>>(qkv, vtb);

    attn_mfma<<<dim3(TT / 64, BB * NHEADS), 256, 0, stream>>>(qb, kb, vtb, attb);

    // out = attn @ w_out^T (M=4096, N=1024, K=1024)
    gemm_bt<<<dim3(1024 / 128, 4096 / 128), 256, 0, stream>>>(attb, wob, out, 4096, 1024, 1024);
}